// Round 4
// baseline (822.770 us; speedup 1.0000x reference)
//
#include <hip/hip_runtime.h>
#include <stdint.h>

namespace {

constexpr int B = 4, C = 128, H = 256, W = 256;
constexpr int V = H * W;              // 65536
constexpr int E = 163072;             // 32640+32512+32640+32512+32768
constexpr long long CHW = (long long)C * V;
constexpr int ROUNDS = 17;

// Edge enumeration matches reference concat order: [L-vert, L-horiz, R-vert, R-horiz, cross]
__device__ __forceinline__ void edge_uv(int e, int& u, int& v) {
  if (e < 32640) {                       // L vertical
    int h = e >> 7, w = e & 127;
    u = (h << 8) + w; v = u + 256;
  } else if (e < 65152) {                // L horizontal
    int k = e - 32640; int h = k / 127, w = k - h * 127;
    u = (h << 8) + w; v = u + 1;
  } else if (e < 97792) {                // R vertical
    int k = e - 65152; int h = k >> 7, w = k & 127;
    u = (h << 8) + 128 + w; v = u + 256;
  } else if (e < 130304) {               // R horizontal
    int k = e - 97792; int h = k / 127, w = k - h * 127;
    u = (h << 8) + 128 + w; v = u + 1;
  } else {                               // cross
    int k = e - 130304; int h = k >> 7, w = k & 127;
    u = (h << 8) + w; v = u + 128;
  }
}

// Chase to effective root: self-loop, or min-id member of a 2-cycle
// (== reference cyc-break). Verified exact in R1-R3.
__device__ __forceinline__ int find_root(const int* __restrict__ par, int v) {
  int cur = v;
  for (int g = 0; g < 70000; ++g) {
    int p = par[cur];
    if (p == cur) break;
    int gp = par[p];
    if (gp == cur) { cur = cur < p ? cur : p; break; }
    cur = p;
  }
  return cur;
}

// Fused pass: per-pixel thread computes own+neighbor fp64 norms and the <=3
// dots for edges it owns (down/right/cross), emits wkeys (bit-identical math
// to R3: same fma chains, same sqrt/div/round), zeroes those out slots, and
// inits parent/minE/cnt.
__global__ void k_weight_init(const float* __restrict__ x,
                              unsigned long long* __restrict__ wkey,
                              float* __restrict__ out,
                              int* __restrict__ parent,
                              unsigned long long* __restrict__ minE,
                              int* __restrict__ cnt) {
  int idx = blockIdx.x * blockDim.x + threadIdx.x;   // exact B*V grid
  int b = idx >> 16, p = idx & (V - 1);
  int h = p >> 8, w = p & 255;
  bool isL  = w < 128;
  bool hasD = h < 255;                               // vertical edge (within own half)
  bool hasR = isL ? (w < 127) : (w < 255);           // horizontal edge
  bool hasX = isL;                                   // cross edge

  const float* xb = x + (long long)b * CHW + p;
  double n0 = 0, ndn = 0, nrt = 0, nxr = 0, dd = 0, dr = 0, dx = 0;
#pragma unroll 4
  for (int c = 0; c < C; ++c) {
    long long off = (long long)c * V;
    double a = (double)xb[off];
    n0 = fma(a, a, n0);
    if (hasD) { double t = (double)xb[off + 256]; ndn = fma(t, t, ndn); dd = fma(a, t, dd); }
    if (hasR) { double t = (double)xb[off + 1];   nrt = fma(t, t, nrt); dr = fma(a, t, dr); }
    if (hasX) { double t = (double)xb[off + 128]; nxr = fma(t, t, nxr); dx = fma(a, t, dx); }
  }

  auto emit = [&](int e, double nu, double nv, double dot) {
    double denom = fmax(sqrt(nu) * sqrt(nv), 1e-8);
    float wv = (float)(dot / denom);
    unsigned int bits = __float_as_uint(wv);
    if (wv == 0.0f) bits = 0u;                       // collapse -0.0
    unsigned int mapped = bits ^ (((int)bits < 0) ? 0xFFFFFFFFu : 0x80000000u);
    wkey[b * E + e] = ((unsigned long long)mapped << 32) | (unsigned int)e;
    out[b * E + e] = 0.0f;
  };
  if (hasD) emit(isL ? ((h << 7) + w) : (65152 + (h << 7) + (w - 128)), n0, ndn, dd);
  if (hasR) emit(isL ? (32640 + h * 127 + w) : (97792 + h * 127 + (w - 128)), n0, nrt, dr);
  if (hasX) emit(130304 + (h << 7) + w, n0, nxr, dx);

  parent[idx] = p;
  minE[idx] = ~0ULL;
  if (idx <= ROUNDS) cnt[idx] = 0;
}

// Round phase 1: (a) per-vertex fresh root snapshot; (b) per-edge (compacted
// list) min-key atomics + append survivors for next round.
__global__ void k_edgemin(const int* __restrict__ parent, int* __restrict__ root,
                          const unsigned long long* __restrict__ wkey,
                          unsigned long long* __restrict__ minE,
                          const int* __restrict__ el_in, int* __restrict__ el_out,
                          int* __restrict__ cnt, int r) {
  int n = (r == 0) ? B * E
                   : __hip_atomic_load(cnt + r, __ATOMIC_RELAXED, __HIP_MEMORY_SCOPE_AGENT);
  if (n == 0) return;                                // converged: no-op round
  int tid = blockIdx.x * blockDim.x + threadIdx.x;

  if (tid < B * V) {                                 // phase (a): root snapshot
    int b = tid >> 16;
    root[tid] = find_root(parent + (b << 16), tid & (V - 1));
  }

  bool sur = false;
  int idx2 = 0;
  if (tid < n) {                                     // phase (b): edges
    idx2 = (r == 0) ? tid : el_in[tid];
    int b = idx2 / E, e = idx2 - b * E;
    int u, v; edge_uv(e, u, v);
    const int* par = parent + (b << 16);
    int ru = find_root(par, u);
    int rv = find_root(par, v);
    if (ru != rv) {
      sur = true;
      unsigned long long k = wkey[idx2];
      unsigned long long* mb = minE + (b << 16);
      atomicMin(mb + ru, k);
      atomicMin(mb + rv, k);
    }
  }
  // wave-aggregated append of surviving edges (set is deterministic; order
  // within the list is irrelevant: atomicMin + idempotent marking commute)
  unsigned long long msk = __ballot(sur);
  if (msk) {
    int lane = threadIdx.x & 63;
    int leader = __ffsll(msk) - 1;
    int base = 0;
    if (lane == leader)
      base = atomicAdd(cnt + r + 1, (int)__popcll(msk));
    base = __shfl(base, leader);
    if (sur)
      el_out[base + (int)__popcll(msk & ((1ULL << lane) - 1))] = idx2;
  }
}

// Round phase 2: mark winners, hook roots, path-compress, re-arm minE.
__global__ void k_hook(const int* __restrict__ root,
                       unsigned long long* __restrict__ minE,
                       int* __restrict__ parent, float* __restrict__ out,
                       const int* __restrict__ cnt, int r) {
  if (__hip_atomic_load(cnt + r + 1, __ATOMIC_RELAXED,
                        __HIP_MEMORY_SCOPE_AGENT) == 0)
    return;                                          // nothing merged this round
  int idx = blockIdx.x * blockDim.x + threadIdx.x;   // exact B*V grid
  int b = idx >> 16, v = idx & (V - 1);
  int rr = root[idx];
  int np = rr;                                       // compression (non-roots)
  if (rr == v) {
    unsigned long long k = minE[idx];
    if (k != ~0ULL) {
      int e = (int)(k & 0xFFFFFFFFu);
      int eu, ev; edge_uv(e, eu, ev);
      const int* rt = root + (b << 16);
      int ru = rt[eu], rv2 = rt[ev];
      out[b * E + e] = 1.0f;                         // winner (idempotent dup)
      np = (v == ru) ? rv2 : ru;                     // hook to other component
    }
  }
  parent[idx] = np;
  minE[idx] = ~0ULL;                                 // re-arm for next round
}

} // namespace

extern "C" void kernel_launch(void* const* d_in, const int* in_sizes, int n_in,
                              void* d_out, int out_size, void* d_ws, size_t ws_size,
                              hipStream_t stream) {
  const float* x = (const float*)d_in[0];
  float* out = (float*)d_out;

  char* ws = (char*)d_ws;
  size_t off = 0;
  auto alloc = [&](size_t bytes) {
    void* p = (void*)(ws + off);
    off += (bytes + 255) & ~(size_t)255;
    return p;
  };
  int* parent = (int*)alloc((size_t)B * V * sizeof(int));                      // 1 MB
  int* root   = (int*)alloc((size_t)B * V * sizeof(int));                      // 1 MB
  unsigned long long* minE = (unsigned long long*)alloc((size_t)B * V * 8);    // 2 MB
  unsigned long long* wkey = (unsigned long long*)alloc((size_t)B * E * 8);    // ~5 MB
  int* elA = (int*)alloc((size_t)B * E * sizeof(int));                         // ~2.6 MB
  int* elB = (int*)alloc((size_t)B * E * sizeof(int));                         // ~2.6 MB
  int* cnt = (int*)alloc((ROUNDS + 1) * sizeof(int));

  k_weight_init<<<(B * V) / 256, 256, 0, stream>>>(x, wkey, out, parent, minE, cnt);

  for (int r = 0; r < ROUNDS; ++r) {
    int* el_in  = (r & 1) ? elA : elB;   // r=0 reads nothing (implicit full set)
    int* el_out = (r & 1) ? elB : elA;
    k_edgemin<<<(B * E) / 256, 256, 0, stream>>>(parent, root, wkey, minE,
                                                 el_in, el_out, cnt, r);
    k_hook   <<<(B * V) / 256, 256, 0, stream>>>(root, minE, parent, out, cnt, r);
  }
}

// Round 5
// 685.732 us; speedup vs baseline: 1.1998x; 1.1998x over previous
//
#include <hip/hip_runtime.h>
#include <stdint.h>

namespace {

constexpr int B = 4, C = 128, H = 256, W = 256;
constexpr int V = H * W;              // 65536
constexpr int E = 163072;             // 32640+32512+32640+32512+32768
constexpr long long CHW = (long long)C * V;
constexpr int ROUNDS = 17;

// Edge enumeration matches reference concat order: [L-vert, L-horiz, R-vert, R-horiz, cross]
__device__ __forceinline__ void edge_uv(int e, int& u, int& v) {
  if (e < 32640) {                       // L vertical
    int h = e >> 7, w = e & 127;
    u = (h << 8) + w; v = u + 256;
  } else if (e < 65152) {                // L horizontal
    int k = e - 32640; int h = k / 127, w = k - h * 127;
    u = (h << 8) + w; v = u + 1;
  } else if (e < 97792) {                // R vertical
    int k = e - 65152; int h = k >> 7, w = k & 127;
    u = (h << 8) + 128 + w; v = u + 256;
  } else if (e < 130304) {               // R horizontal
    int k = e - 97792; int h = k / 127, w = k - h * 127;
    u = (h << 8) + 128 + w; v = u + 1;
  } else {                               // cross
    int k = e - 130304; int h = k >> 7, w = k & 127;
    u = (h << 8) + w; v = u + 128;
  }
}

// Chase to effective root: self-loop, or min-id member of a 2-cycle
// (== reference cyc-break). Verified exact in R1-R4.
__device__ __forceinline__ int find_root(const int* __restrict__ par, int v) {
  int cur = v;
  for (int g = 0; g < 70000; ++g) {
    int p = par[cur];
    if (p == cur) break;
    int gp = par[p];
    if (gp == cur) { cur = cur < p ? cur : p; break; }
    cur = p;
  }
  return cur;
}

// Pass 1: per-pixel squared norm (fp64 accumulate) + parent/minE/cnt init.
__global__ void k_norm_init(const float* __restrict__ x, double* __restrict__ n2,
                            int* __restrict__ parent, unsigned long long* __restrict__ minE,
                            int* __restrict__ cnt) {
  int idx = blockIdx.x * blockDim.x + threadIdx.x;   // exact B*V grid
  int b = idx >> 16, p = idx & (V - 1);
  const float* xb = x + (long long)b * CHW + p;
  double acc = 0.0;
#pragma unroll 8
  for (int c = 0; c < C; ++c) {
    double t = (double)xb[(long long)c * V];
    acc = fma(t, t, acc);
  }
  n2[idx] = acc;
  parent[idx] = p;
  minE[idx] = ~0ULL;
  if (idx <= ROUNDS) cnt[idx] = 0;
}

// Pass 2: per-edge cosine (fp64 dot), round once to fp32, pack sortable key.
// Bit-identical math to the R1/R3 version that passed exact. Also zeroes out.
__global__ void k_weight(const float* __restrict__ x, const double* __restrict__ n2,
                         unsigned long long* __restrict__ wkey, float* __restrict__ out) {
  int idx = blockIdx.x * blockDim.x + threadIdx.x;   // exact B*E grid
  int b = idx / E, e = idx - b * E;
  int u, v; edge_uv(e, u, v);
  const float* xb = x + (long long)b * CHW;
  double dot = 0.0;
#pragma unroll 8
  for (int c = 0; c < C; ++c) {
    long long off = (long long)c * V;
    dot = fma((double)xb[off + u], (double)xb[off + v], dot);
  }
  double denom = fmax(sqrt(n2[(b << 16) + u]) * sqrt(n2[(b << 16) + v]), 1e-8);
  float w = (float)(dot / denom);
  unsigned int bits = __float_as_uint(w);
  if (w == 0.0f) bits = 0u;                          // collapse -0.0
  unsigned int mapped = bits ^ (((int)bits < 0) ? 0xFFFFFFFFu : 0x80000000u);
  wkey[idx] = ((unsigned long long)mapped << 32) | (unsigned int)e;
  out[idx] = 0.0f;
}

// Round phase 1: per-edge over the COMPACTED survivor list (grid-stride,
// small fixed grid). Chase both roots, publish them for winner lookup,
// atomicMin per component, append still-cross edges for next round.
__global__ void k_edgemin(const int* __restrict__ parent, int* __restrict__ root,
                          const unsigned long long* __restrict__ wkey,
                          unsigned long long* __restrict__ minE,
                          const int* __restrict__ el_in, int* __restrict__ el_out,
                          int* __restrict__ cnt, int r) {
  int n = (r == 0) ? B * E
                   : __hip_atomic_load(cnt + r, __ATOMIC_RELAXED, __HIP_MEMORY_SCOPE_AGENT);
  if (n == 0) return;                                // converged: cheap no-op
  int T = gridDim.x * blockDim.x;
  int tid = blockIdx.x * blockDim.x + threadIdx.x;

  for (int i = tid; i < n + (T - 1); i += T) {       // keep waves together for ballot
    bool live = i < n;
    bool sur = false;
    int idx2 = 0;
    if (live) {
      idx2 = (r == 0) ? i : el_in[i];
      int b = idx2 / E, e = idx2 - b * E;
      int u, v; edge_uv(e, u, v);
      const int* par = parent + (b << 16);
      int ru = find_root(par, u);
      int rv = find_root(par, v);
      if (ru != rv) {
        sur = true;
        int* rt = root + (b << 16);
        rt[u] = ru;                                  // fresh roots for winner lookup
        rt[v] = rv;
        unsigned long long k = wkey[idx2];
        unsigned long long* mb = minE + (b << 16);
        atomicMin(mb + ru, k);
        atomicMin(mb + rv, k);
      }
    }
    // wave-aggregated append (list order irrelevant: atomicMin + idempotent
    // marking commute; the surviving SET is deterministic)
    unsigned long long msk = __ballot(sur);
    if (msk) {
      int lane = threadIdx.x & 63;
      int leader = __ffsll(msk) - 1;
      int base = 0;
      if (lane == leader)
        base = atomicAdd(cnt + r + 1, (int)__popcll(msk));
      base = __shfl(base, leader);
      if (sur)
        el_out[base + (int)__popcll(msk & ((1ULL << lane) - 1))] = idx2;
    }
  }
}

// Round phase 2 (per vertex): chase own root (identical value to the old
// precomputed root[]), mark winner, hook, compress-on-change, re-arm only
// the dirtied minE slots (exactly the current-root slots atomicMin touched).
__global__ void k_hook(unsigned long long* __restrict__ minE,
                       const int* __restrict__ root,
                       int* __restrict__ parent, float* __restrict__ out,
                       const int* __restrict__ cnt, int r) {
  if (__hip_atomic_load(cnt + r + 1, __ATOMIC_RELAXED,
                        __HIP_MEMORY_SCOPE_AGENT) == 0)
    return;                                          // nothing merged this round
  int idx = blockIdx.x * blockDim.x + threadIdx.x;   // exact B*V grid
  int b = idx >> 16, v = idx & (V - 1);
  const int* par = parent + (b << 16);
  int old = par[v];
  int rr = find_root(par, v);
  int np = rr;                                       // compression (non-roots)
  if (rr == v) {
    unsigned long long k = minE[idx];
    if (k != ~0ULL) {
      int e = (int)(k & 0xFFFFFFFFu);
      int eu, ev; edge_uv(e, eu, ev);
      const int* rt = root + (b << 16);
      int ru = rt[eu], rv2 = rt[ev];                 // fresh: e survived this round
      out[b * E + e] = 1.0f;                         // winner (idempotent dup)
      np = (v == ru) ? rv2 : ru;                     // hook to other component
      minE[idx] = ~0ULL;                             // re-arm dirtied slot
    }
  }
  if (np != old) parent[idx] = np;
}

} // namespace

extern "C" void kernel_launch(void* const* d_in, const int* in_sizes, int n_in,
                              void* d_out, int out_size, void* d_ws, size_t ws_size,
                              hipStream_t stream) {
  const float* x = (const float*)d_in[0];
  float* out = (float*)d_out;

  char* ws = (char*)d_ws;
  size_t off = 0;
  auto alloc = [&](size_t bytes) {
    void* p = (void*)(ws + off);
    off += (bytes + 255) & ~(size_t)255;
    return p;
  };
  int* parent = (int*)alloc((size_t)B * V * sizeof(int));                      // 1 MB
  int* root   = (int*)alloc((size_t)B * V * sizeof(int));                      // 1 MB
  unsigned long long* minE = (unsigned long long*)alloc((size_t)B * V * 8);    // 2 MB
  double* n2  = (double*)alloc((size_t)B * V * sizeof(double));                // 2 MB
  unsigned long long* wkey = (unsigned long long*)alloc((size_t)B * E * 8);    // ~5 MB
  int* elA = (int*)alloc((size_t)B * E * sizeof(int));                         // ~2.6 MB
  int* elB = (int*)alloc((size_t)B * E * sizeof(int));                         // ~2.6 MB
  int* cnt = (int*)alloc((ROUNDS + 1) * sizeof(int));

  k_norm_init<<<(B * V) / 256, 256, 0, stream>>>(x, n2, parent, minE, cnt);
  k_weight<<<(B * E) / 256, 256, 0, stream>>>(x, n2, wkey, out);

  for (int r = 0; r < ROUNDS; ++r) {
    int* el_in  = (r & 1) ? elA : elB;   // r=0 reads nothing (implicit full set)
    int* el_out = (r & 1) ? elB : elA;
    k_edgemin<<<1024, 256, 0, stream>>>(parent, root, wkey, minE,
                                        el_in, el_out, cnt, r);
    k_hook   <<<(B * V) / 256, 256, 0, stream>>>(minE, root, parent, out, cnt, r);
  }
}